// Round 5
// baseline (2078.074 us; speedup 1.0000x reference)
//
#include <hip/hip_runtime.h>

typedef _Float16 half8 __attribute__((ext_vector_type(8)));
typedef _Float16 half4v __attribute__((ext_vector_type(4)));
typedef float f32x4 __attribute__((ext_vector_type(4)));

#define MFMA_F16 __builtin_amdgcn_mfma_f32_16x16x32_f16

static constexpr int BATCH  = 4096;
static constexpr int DIM    = 512;
static constexpr int CODES  = 16384;
static constexpr int NCB    = 8;
static constexpr int NCHUNK = 8;
static constexpr int CHUNK  = CODES / NCHUNK;   // 2048
static constexpr int NT     = CHUNK / 16;       // 128 tiles of 16 codes
static constexpr int BM     = 128;              // rows per block (4 pairs x 32)
static constexpr int TILE_H = 16384;            // halfs per tile (hi 8192 | lo 8192) = 32KB
static constexpr int TILE_B = 32768;            // tile bytes
static constexpr float LO_SCALE = 2048.0f;
static constexpr float LO_INV   = 1.0f / 2048.0f;

// legacy swizzle (fallback path only)
__device__ __forceinline__ int swz(int code, int kk) {
  return code * DIM + (kk ^ (((code ^ (kk >> 6)) & 7) << 3));
}

__device__ __forceinline__ void dma16(const void* g, void* l) {
  __builtin_amdgcn_global_load_lds(
      (const __attribute__((address_space(1))) unsigned int*)g,
      (__attribute__((address_space(3))) unsigned int*)l, 16, 0, 0);
}

// ---------------- init: residual = z, plus f16 hi/lo split ----------------
__global__ __launch_bounds__(256) void k_init(const float* __restrict__ z,
                                              float* __restrict__ resid,
                                              _Float16* __restrict__ rhi,
                                              _Float16* __restrict__ rlo) {
  int i = blockIdx.x * 256 + threadIdx.x;      // float4 index, 524288 total
  float4 v = ((const float4*)z)[i];
  ((float4*)resid)[i] = v;
  half4v h, l;
  const float* vf = (const float*)&v;
#pragma unroll
  for (int j = 0; j < 4; ++j) {
    float x = vf[j];
    _Float16 hi = (_Float16)x;
    h[j] = hi;
    l[j] = (_Float16)((x - (float)hi) * LO_SCALE);
  }
  *(half4v*)&rhi[(size_t)i * 4] = h;
  *(half4v*)&rlo[(size_t)i * 4] = l;
}

// ---------------- codebook squared norms (f64 accumulate) ----------------
__global__ __launch_bounds__(256) void k_cnorm(const float* __restrict__ cb,
                                               float* __restrict__ cnorm) {
  int wave = threadIdx.x >> 6, lane = threadIdx.x & 63;
  int code = blockIdx.x * 4 + wave;            // 131072 codes total
  const float4* src = (const float4*)(cb + (size_t)code * DIM);
  double s = 0.0;
#pragma unroll
  for (int j = 0; j < 2; ++j) {
    float4 v = src[lane * 2 + j];
    s += (double)v.x * v.x + (double)v.y * v.y + (double)v.z * v.z + (double)v.w * v.w;
  }
#pragma unroll
  for (int off = 32; off; off >>= 1) s += __shfl_down(s, off);
  if (lane == 0) cnorm[code] = (float)s;
}

// ---------------- preconvert codebook k: lane-linear tile images ----------------
// Per 16-code tile: hi image halfs [0,8192): pos = t*512 + kbg*128 + code*8 + e
// (t: K-slice of 32, kbg = k-quarter, e in [0,8)); lo image at +8192.
// Hot-loop read for lane l, slice t is byte (t*1024 + l*16) — fully linear.
__global__ __launch_bounds__(256) void k_cvt(const float* __restrict__ cb,
                                             _Float16* __restrict__ dst) {
  const int chunk = blockIdx.x & 7;                        // XCD-pinned
  const int idx8  = (blockIdx.x >> 3) * 256 + threadIdx.x; // [0, 131072) half8-slots
  const int ntile = idx8 >> 10;
  const int rem8  = idx8 & 1023;
  const int p     = rem8 * 8;
  const int t     = p >> 9;
  const int kbg   = (p >> 7) & 3;
  const int code  = (p >> 3) & 15;
  const int code_g = chunk * CHUNK + ntile * 16 + code;
  const float* src = cb + (size_t)code_g * DIM + t * 32 + kbg * 8;
  float4 v0 = *(const float4*)src;
  float4 v1 = *(const float4*)(src + 4);
  half8 h, l;
  const float* f0 = (const float*)&v0;
  const float* f1 = (const float*)&v1;
#pragma unroll
  for (int e = 0; e < 4; ++e) {
    float x = f0[e];
    _Float16 hi = (_Float16)x;
    h[e] = hi; l[e] = (_Float16)((x - (float)hi) * LO_SCALE);
    x = f1[e];
    hi = (_Float16)x;
    h[e + 4] = hi; l[e + 4] = (_Float16)((x - (float)hi) * LO_SCALE);
  }
  size_t tb = (size_t)(chunk * NT + ntile) * TILE_H;
  *(half8*)(dst + tb + rem8 * 8) = h;
  *(half8*)(dst + tb + 8192 + rem8 * 8) = l;
}

// ---------------- per-step argmin: 512 threads, 3-buffer counted-vmcnt pipeline ----
// 8 waves: pair p = wave>>1 owns rows [32p,32p+32); kh = wave&1 owns a K-half.
// 32 mtiles x 8 chunks = 256 blocks = 1 per CU.
__global__ __launch_bounds__(512, 2) void k_argmin_pc(
    const _Float16* __restrict__ rhi, const _Float16* __restrict__ rlo,
    const _Float16* __restrict__ cvt,
    const float* __restrict__ cnorm,
    float* __restrict__ partmin, int* __restrict__ partidx) {
  __shared__ _Float16 B[3][TILE_H];    // 96 KB triple-buffered tile
  __shared__ float    Xs[4 * 2 * 2 * 64 * 4]; // 16 KB pair-exchange
  __shared__ float    CN[CHUNK];       // 8 KB code norms

  const int tid   = threadIdx.x;
  const int lane  = tid & 63;
  const int wave  = tid >> 6;          // 0..7
  const int pairp = wave >> 1;         // 0..3
  const int kh    = wave & 1;
  const int mtile = blockIdx.x >> 3;   // 0..31
  const int chunk = blockIdx.x & 7;    // XCD-pinned chunk
  const int cbase = chunk * CHUNK;
  const char* ctile = (const char*)(cvt + (size_t)chunk * NT * TILE_H);

  // stage cnorm chunk to LDS (512 threads x 1 float4 = 2048 floats)
  ((float4*)CN)[tid] = ((const float4*)(cnorm + cbase))[tid];

  // A fragments: 32 rows (2 mtiles), own K-half. lane: row=lane&15, kb=(lane>>4)*8
  const int kb = (lane >> 4) * 8;
  half8 ah[2][8], al[2][8];
#pragma unroll
  for (int mt = 0; mt < 2; ++mt) {
    const size_t rbase =
        (size_t)(mtile * BM + pairp * 32 + mt * 16 + (lane & 15)) * DIM + kh * 256;
#pragma unroll
    for (int t = 0; t < 8; ++t) {
      ah[mt][t] = *(const half8*)(rhi + rbase + t * 32 + kb);
      al[mt][t] = *(const half8*)(rlo + rbase + t * 32 + kb);
    }
  }

  // drain A-loads + CN stage so vmcnt counts only tile DMAs from here on
  asm volatile("s_waitcnt vmcnt(0) lgkmcnt(0)" ::: "memory");

  // DMA map: wave w covers tile bytes [w*4096, (w+1)*4096) in 4 rounds of 1KB
  const int gl = wave * 4096 + lane * 16;

  // prologue: issue tiles 0 and 1 (4 dma16 per wave each -> 8 outstanding)
#pragma unroll
  for (int tt = 0; tt < 2; ++tt) {
    const char* gt = ctile + tt * TILE_B + gl;
    char* lp = (char*)&B[tt][0] + wave * 4096;
#pragma unroll
    for (int r = 0; r < 4; ++r)
      dma16(gt + r * 1024, lp + r * 1024);
  }

  const int rcode = lane & 15;
  float rmin[2][4] = {{3.4e38f, 3.4e38f, 3.4e38f, 3.4e38f},
                      {3.4e38f, 3.4e38f, 3.4e38f, 3.4e38f}};
  int   ridx[2][4] = {{0, 0, 0, 0}, {0, 0, 0, 0}};

  int cur = 0;   // buffer holding tile nt (cycles 0,1,2)
  for (int nt = 0; nt < NT; ++nt) {
    // wait for tile nt only: tile nt+1's 4 loads stay in flight across the barrier
    if (nt < NT - 1) asm volatile("s_waitcnt vmcnt(4)" ::: "memory");
    else             asm volatile("s_waitcnt vmcnt(0)" ::: "memory");
    __builtin_amdgcn_s_barrier();
    __builtin_amdgcn_sched_barrier(0);

    // issue tile nt+2 into the buffer freed by iteration nt-1
    if (nt + 2 < NT) {
      const int nb = (cur + 2 >= 3) ? cur - 1 : cur + 2;
      const char* gt = ctile + (size_t)(nt + 2) * TILE_B + gl;
      char* lp = (char*)&B[nb][0] + wave * 4096;
#pragma unroll
      for (int r = 0; r < 4; ++r)
        dma16(gt + r * 1024, lp + r * 1024);
    }
    __builtin_amdgcn_sched_barrier(0);

    const char* bb = (const char*)&B[cur][0];
    const float cn = CN[nt * 16 + rcode];

    f32x4 acch[2], accl0[2], accl1[2];
#pragma unroll
    for (int mt = 0; mt < 2; ++mt) {
      acch[mt]  = (f32x4){0.f, 0.f, 0.f, 0.f};
      accl0[mt] = (f32x4){0.f, 0.f, 0.f, 0.f};
      accl1[mt] = (f32x4){0.f, 0.f, 0.f, 0.f};
    }
#pragma unroll
    for (int t = 0; t < 8; ++t) {
      const int ro = (kh * 8 + t) * 1024 + lane * 16;   // lane-linear, conflict-free
      half8 fbh = *(const half8*)(bb + ro);
      half8 fbl = *(const half8*)(bb + 16384 + ro);
#pragma unroll
      for (int mt = 0; mt < 2; ++mt) {
        acch[mt]  = MFMA_F16(ah[mt][t], fbh, acch[mt], 0, 0, 0);
        accl0[mt] = MFMA_F16(ah[mt][t], fbl, accl0[mt], 0, 0, 0);
        accl1[mt] = MFMA_F16(al[mt][t], fbh, accl1[mt], 0, 0, 0);
      }
    }

    // pre-combined half-distance dot terms; exchange within the pair
    f32x4 dh[2];
#pragma unroll
    for (int mt = 0; mt < 2; ++mt) {
      dh[mt] = acch[mt] + (accl0[mt] + accl1[mt]) * LO_INV;
      *(f32x4*)&Xs[(((pairp * 2 + kh) * 2 + mt) * 64 + lane) * 4] = dh[mt];
    }
    asm volatile("s_waitcnt lgkmcnt(0)" ::: "memory");   // Xs visible; DMAs untouched
    __builtin_amdgcn_s_barrier();
    __builtin_amdgcn_sched_barrier(0);

    const int codeg = cbase + nt * 16 + rcode;
#pragma unroll
    for (int mt = 0; mt < 2; ++mt) {
      f32x4 dp = *(const f32x4*)&Xs[(((pairp * 2 + (kh ^ 1)) * 2 + mt) * 64 + lane) * 4];
      f32x4 dt = dh[mt] + dp;       // commutative: both waves get identical values
#pragma unroll
      for (int r = 0; r < 4; ++r) {
        float d = cn - 2.0f * dt[r];
        if (d < rmin[mt][r]) { rmin[mt][r] = d; ridx[mt][r] = codeg; }  // first-min
      }
    }
    cur = (cur + 1 == 3) ? 0 : cur + 1;
  }

  // butterfly min across the 16-lane column group (tie -> smaller index)
#pragma unroll
  for (int s = 1; s < 16; s <<= 1) {
#pragma unroll
    for (int mt = 0; mt < 2; ++mt) {
#pragma unroll
      for (int r = 0; r < 4; ++r) {
        float ov = __shfl_xor(rmin[mt][r], s);
        int   oi = __shfl_xor(ridx[mt][r], s);
        if (ov < rmin[mt][r] || (ov == rmin[mt][r] && oi < ridx[mt][r])) {
          rmin[mt][r] = ov; ridx[mt][r] = oi;
        }
      }
    }
  }
  if (kh == 0 && (lane & 15) == 0) {
#pragma unroll
    for (int mt = 0; mt < 2; ++mt) {
      int rowbase = mtile * BM + pairp * 32 + mt * 16 + (lane >> 4) * 4;
#pragma unroll
      for (int r = 0; r < 4; ++r) {
        partmin[(size_t)(rowbase + r) * NCHUNK + chunk] = rmin[mt][r];
        partidx[(size_t)(rowbase + r) * NCHUNK + chunk] = ridx[mt][r];
      }
    }
  }
}

// ---------------- fallback argmin (round-1 structure, inline conversion) ----------------
__device__ __forceinline__ void load8(const float* __restrict__ cb, int cbase, int nt,
                                      int s_code, int s_kseg, float4 v[8]) {
  const float4* src = (const float4*)(cb + (size_t)(cbase + nt * 16 + s_code) * DIM + s_kseg);
#pragma unroll
  for (int j = 0; j < 8; ++j) v[j] = src[j];
}

__device__ __forceinline__ void cvt_store(_Float16* __restrict__ BHbuf,
                                          _Float16* __restrict__ BLbuf,
                                          int code, int kseg, const float4 sv[8]) {
  const float* f = (const float*)sv;
#pragma unroll
  for (int j = 0; j < 4; ++j) {
    half8 h, l;
#pragma unroll
    for (int e = 0; e < 8; ++e) {
      float x = f[j * 8 + e];
      _Float16 hi = (_Float16)x;
      h[e] = hi;
      l[e] = (_Float16)((x - (float)hi) * LO_SCALE);
    }
    int hw = swz(code, kseg + j * 8);
    *(half8*)(BHbuf + hw) = h;
    *(half8*)(BLbuf + hw) = l;
  }
}

__global__ __launch_bounds__(256, 2) void k_argmin_fb(
    const _Float16* __restrict__ rhi, const _Float16* __restrict__ rlo,
    const float* __restrict__ cb, const float* __restrict__ cnorm,
    float* __restrict__ partmin, int* __restrict__ partidx) {
  __shared__ _Float16 BH[2][16 * DIM];
  __shared__ _Float16 BL[2][16 * DIM];
  __shared__ float CN[CHUNK];

  const int tid   = threadIdx.x;
  const int lane  = tid & 63;
  const int wave  = tid >> 6;
  const int mtile = blockIdx.x >> 3;
  const int chunk = blockIdx.x & 7;
  const int cbase = chunk * CHUNK;

  {
    const float4* s = (const float4*)(cnorm + cbase);
    float4* d = (float4*)CN;
    for (int i = tid; i < CHUNK / 4; i += 256) d[i] = s[i];
  }

  const int arow = mtile * 64 + wave * 16 + (lane & 15);
  const int kb = (lane >> 4) * 8;
  half8 ah[16], al[16];
#pragma unroll
  for (int t = 0; t < 16; ++t) {
    ah[t] = *(const half8*)(rhi + (size_t)arow * DIM + t * 32 + kb);
    al[t] = *(const half8*)(rlo + (size_t)arow * DIM + t * 32 + kb);
  }

  const int s_code = tid >> 4;
  const int s_kseg = (tid & 15) * 32;

  float rmin[4] = {3.4e38f, 3.4e38f, 3.4e38f, 3.4e38f};
  int   ridx[4] = {0, 0, 0, 0};

  {
    float4 v0[8];
    load8(cb, cbase, 0, s_code, s_kseg, v0);
    cvt_store(&BH[0][0], &BL[0][0], s_code, s_kseg, v0);
  }

  const int rcode = lane & 15;
  for (int nt = 0; nt < NT; ++nt) {
    __syncthreads();
    const int cur = nt & 1;
    const bool more = (nt + 1 < NT);
    float4 nv[8];
    if (more) load8(cb, cbase, nt + 1, s_code, s_kseg, nv);

    f32x4 acch  = {0.f, 0.f, 0.f, 0.f};
    f32x4 accl0 = {0.f, 0.f, 0.f, 0.f};
    f32x4 accl1 = {0.f, 0.f, 0.f, 0.f};
    const _Float16* bh = &BH[cur][0];
    const _Float16* bl = &BL[cur][0];
#pragma unroll
    for (int t = 0; t < 16; ++t) {
      const int hw = swz(rcode, t * 32 + kb);
      half8 fbh = *(const half8*)(bh + hw);
      half8 fbl = *(const half8*)(bl + hw);
      acch  = MFMA_F16(ah[t], fbh, acch, 0, 0, 0);
      accl0 = MFMA_F16(ah[t], fbl, accl0, 0, 0, 0);
      accl1 = MFMA_F16(al[t], fbh, accl1, 0, 0, 0);
    }
    float cn = CN[nt * 16 + rcode];
    int codeg = cbase + nt * 16 + rcode;
#pragma unroll
    for (int r = 0; r < 4; ++r) {
      float d = cn - 2.0f * (acch[r] + (accl0[r] + accl1[r]) * LO_INV);
      if (d < rmin[r]) { rmin[r] = d; ridx[r] = codeg; }
    }
    if (more) cvt_store(&BH[cur ^ 1][0], &BL[cur ^ 1][0], s_code, s_kseg, nv);
  }

#pragma unroll
  for (int s = 1; s < 16; s <<= 1) {
#pragma unroll
    for (int r = 0; r < 4; ++r) {
      float ov = __shfl_xor(rmin[r], s);
      int   oi = __shfl_xor(ridx[r], s);
      if (ov < rmin[r] || (ov == rmin[r] && oi < ridx[r])) { rmin[r] = ov; ridx[r] = oi; }
    }
  }
  if ((lane & 15) == 0) {
    int rowbase = mtile * 64 + wave * 16 + (lane >> 4) * 4;
#pragma unroll
    for (int r = 0; r < 4; ++r) {
      partmin[(size_t)(rowbase + r) * NCHUNK + chunk] = rmin[r];
      partidx[(size_t)(rowbase + r) * NCHUNK + chunk] = ridx[r];
    }
  }
}

// ---------------- reduce chunks, gather, update residual/quantized/loss ----------------
__global__ __launch_bounds__(256) void k_update(
    const float* __restrict__ cb, const float* __restrict__ z,
    const float* __restrict__ partmin, const int* __restrict__ partidx,
    float* __restrict__ resid, _Float16* __restrict__ rhi, _Float16* __restrict__ rlo,
    float* __restrict__ quant, float* __restrict__ out_idx,
    float* __restrict__ losspart, int step) {
  __shared__ int s_idx[16];
  __shared__ float s_red[4];
  const int tid = threadIdx.x;
  const int row0 = blockIdx.x * 16;

  if (tid < 16) {
    const int row = row0 + tid;
    float bv = partmin[(size_t)row * NCHUNK];
    int   bi = partidx[(size_t)row * NCHUNK];
#pragma unroll
    for (int c = 1; c < NCHUNK; ++c) {
      float v = partmin[(size_t)row * NCHUNK + c];
      int   i = partidx[(size_t)row * NCHUNK + c];
      if (v < bv || (v == bv && i < bi)) { bv = v; bi = i; }
    }
    s_idx[tid] = bi;
    out_idx[(size_t)row * NCB + step] = (float)bi;
  }
  __syncthreads();

  float lsum = 0.f;
  const int sub = tid >> 7;     // 0/1: which row of the pair
  const int e   = tid & 127;    // float4 index within row
  for (int rp = 0; rp < 16; rp += 2) {
    const int rl = rp + sub;
    const int row = row0 + rl;
    const int idx = s_idx[rl];
    float4 q  = ((const float4*)cb)[(size_t)idx * 128 + e];
    float4 zv = ((const float4*)z)[(size_t)row * 128 + e];
    float4 rv = ((const float4*)resid)[(size_t)row * 128 + e];
    float4 nr, qa;
    const float* qf = (const float*)&q;
    const float* zf = (const float*)&zv;
    const float* rf = (const float*)&rv;
    float* nf = (float*)&nr;
    float* af = (float*)&qa;
    if (step == 0) {
#pragma unroll
      for (int j = 0; j < 4; ++j) af[j] = qf[j];
    } else {
      float4 old = ((const float4*)quant)[(size_t)row * 128 + e];
      const float* of = (const float*)&old;
#pragma unroll
      for (int j = 0; j < 4; ++j) af[j] = of[j] + qf[j];
    }
    ((float4*)quant)[(size_t)row * 128 + e] = qa;
    half4v h, l;
#pragma unroll
    for (int j = 0; j < 4; ++j) {
      float nrj = rf[j] - qf[j];
      nf[j] = nrj;
      _Float16 hi = (_Float16)nrj;
      h[j] = hi;
      l[j] = (_Float16)((nrj - (float)hi) * LO_SCALE);
      float dq = qf[j] - zf[j];
      lsum += dq * dq;
    }
    ((float4*)resid)[(size_t)row * 128 + e] = nr;
    *(half4v*)&rhi[(size_t)row * DIM + e * 4] = h;
    *(half4v*)&rlo[(size_t)row * DIM + e * 4] = l;
  }
#pragma unroll
  for (int off = 32; off; off >>= 1) lsum += __shfl_down(lsum, off);
  if ((tid & 63) == 0) s_red[tid >> 6] = lsum;
  __syncthreads();
  if (tid == 0) losspart[blockIdx.x] = s_red[0] + s_red[1] + s_red[2] + s_red[3];
}

// ---------------- final loss ----------------
__global__ void k_loss(const float* __restrict__ losspart, float* __restrict__ out_loss) {
  if (threadIdx.x == 0 && blockIdx.x == 0) {
    double t = 0.0;
    for (int i = 0; i < NCB * 256; ++i) t += (double)losspart[i];
    out_loss[0] = (float)(t * (1.25 / (double)((size_t)BATCH * DIM)));
  }
}

extern "C" void kernel_launch(void* const* d_in, const int* in_sizes, int n_in,
                              void* d_out, int out_size, void* d_ws, size_t ws_size,
                              hipStream_t stream) {
  const float* z  = (const float*)d_in[0];
  const float* cb = (const float*)d_in[1];
  float* out = (float*)d_out;
  float* quant    = out;                           // [4096*512]
  float* out_loss = out + (size_t)BATCH * DIM;     // [1]
  float* out_idx  = out + (size_t)BATCH * DIM + 1; // [4096*8] written as float

  char* ws = (char*)d_ws;
  float*    resid    = (float*)ws;                                  // 8 MB
  _Float16* rhi      = (_Float16*)(ws + ((size_t)8  << 20));        // 4 MB
  _Float16* rlo      = (_Float16*)(ws + ((size_t)12 << 20));        // 4 MB
  float*    cnorm    = (float*)(ws + ((size_t)16 << 20));           // 512 KB
  float*    partmin  = (float*)(ws + ((size_t)16 << 20) + (512 << 10)); // 128 KB
  int*      partidx  = (int*)  (ws + ((size_t)16 << 20) + (640 << 10)); // 128 KB
  float*    losspart = (float*)(ws + ((size_t)16 << 20) + (768 << 10)); // 8 KB
  _Float16* cvtbuf   = (_Float16*)(ws + ((size_t)20 << 20));        // 32 MB

  const size_t REQ = ((size_t)20 << 20) + ((size_t)32 << 20);
  const bool pre = (ws_size >= REQ);

  k_init<<<dim3((BATCH * DIM / 4) / 256), dim3(256), 0, stream>>>(z, resid, rhi, rlo);
  k_cnorm<<<dim3(NCB * CODES / 4), dim3(256), 0, stream>>>(cb, cnorm);

  for (int k = 0; k < NCB; ++k) {
    const float* cbk = cb + (size_t)k * CODES * DIM;
    if (pre) {
      k_cvt<<<dim3(CODES * 64 / 256), dim3(256), 0, stream>>>(cbk, cvtbuf);
      k_argmin_pc<<<dim3((BATCH / BM) * NCHUNK), dim3(512), 0, stream>>>(
          rhi, rlo, cvtbuf, cnorm + (size_t)k * CODES, partmin, partidx);
    } else {
      k_argmin_fb<<<dim3((BATCH / 64) * NCHUNK), dim3(256), 0, stream>>>(
          rhi, rlo, cbk, cnorm + (size_t)k * CODES, partmin, partidx);
    }
    k_update<<<dim3(BATCH / 16), dim3(256), 0, stream>>>(
        cbk, z, partmin, partidx, resid, rhi, rlo,
        quant, out_idx, losspart + k * 256, k);
  }
  k_loss<<<dim3(1), dim3(64), 0, stream>>>(losspart, out_loss);
}

// Round 6
// 1899.327 us; speedup vs baseline: 1.0941x; 1.0941x over previous
//
#include <hip/hip_runtime.h>

typedef _Float16 half8 __attribute__((ext_vector_type(8)));
typedef _Float16 half4v __attribute__((ext_vector_type(4)));
typedef float f32x4 __attribute__((ext_vector_type(4)));

#define MFMA_F16 __builtin_amdgcn_mfma_f32_16x16x32_f16

static constexpr int BATCH  = 4096;
static constexpr int DIM    = 512;
static constexpr int CODES  = 16384;
static constexpr int NCB    = 8;
static constexpr int NCHUNK = 8;
static constexpr int CHUNK  = CODES / NCHUNK;   // 2048
static constexpr int NT     = CHUNK / 16;       // 128 tiles of 16 codes
static constexpr int BM     = 64;               // rows per block (2 pairs x 32)
static constexpr int TILE_H = 16384;            // halfs per tile (hi 8192 | lo 8192) = 32KB
static constexpr int TILE_B = 32768;            // tile bytes
static constexpr float LO_SCALE = 2048.0f;
static constexpr float LO_INV   = 1.0f / 2048.0f;

// legacy swizzle (fallback path only)
__device__ __forceinline__ int swz(int code, int kk) {
  return code * DIM + (kk ^ (((code ^ (kk >> 6)) & 7) << 3));
}

// ---------------- init: residual = z, plus f16 hi/lo split ----------------
__global__ __launch_bounds__(256) void k_init(const float* __restrict__ z,
                                              float* __restrict__ resid,
                                              _Float16* __restrict__ rhi,
                                              _Float16* __restrict__ rlo) {
  int i = blockIdx.x * 256 + threadIdx.x;      // float4 index, 524288 total
  float4 v = ((const float4*)z)[i];
  ((float4*)resid)[i] = v;
  half4v h, l;
  const float* vf = (const float*)&v;
#pragma unroll
  for (int j = 0; j < 4; ++j) {
    float x = vf[j];
    _Float16 hi = (_Float16)x;
    h[j] = hi;
    l[j] = (_Float16)((x - (float)hi) * LO_SCALE);
  }
  *(half4v*)&rhi[(size_t)i * 4] = h;
  *(half4v*)&rlo[(size_t)i * 4] = l;
}

// ---------------- codebook squared norms (f64 accumulate) ----------------
__global__ __launch_bounds__(256) void k_cnorm(const float* __restrict__ cb,
                                               float* __restrict__ cnorm) {
  int wave = threadIdx.x >> 6, lane = threadIdx.x & 63;
  int code = blockIdx.x * 4 + wave;            // 131072 codes total
  const float4* src = (const float4*)(cb + (size_t)code * DIM);
  double s = 0.0;
#pragma unroll
  for (int j = 0; j < 2; ++j) {
    float4 v = src[lane * 2 + j];
    s += (double)v.x * v.x + (double)v.y * v.y + (double)v.z * v.z + (double)v.w * v.w;
  }
#pragma unroll
  for (int off = 32; off; off >>= 1) s += __shfl_down(s, off);
  if (lane == 0) cnorm[code] = (float)s;
}

// ---------------- preconvert codebook k: lane-linear tile images ----------------
// Per 16-code tile: hi image halfs [0,8192): pos = t*512 + kbg*128 + code*8 + e
// (t: K-slice of 32, kbg = k-quarter, e in [0,8)); lo image at +8192.
// Hot-loop read for lane l, slice t is byte (t*1024 + l*16) — fully linear.
__global__ __launch_bounds__(256) void k_cvt(const float* __restrict__ cb,
                                             _Float16* __restrict__ dst) {
  const int chunk = blockIdx.x & 7;                        // XCD-pinned
  const int idx8  = (blockIdx.x >> 3) * 256 + threadIdx.x; // [0, 131072) half8-slots
  const int ntile = idx8 >> 10;
  const int rem8  = idx8 & 1023;
  const int p     = rem8 * 8;
  const int t     = p >> 9;
  const int kbg   = (p >> 7) & 3;
  const int code  = (p >> 3) & 15;
  const int code_g = chunk * CHUNK + ntile * 16 + code;
  const float* src = cb + (size_t)code_g * DIM + t * 32 + kbg * 8;
  float4 v0 = *(const float4*)src;
  float4 v1 = *(const float4*)(src + 4);
  half8 h, l;
  const float* f0 = (const float*)&v0;
  const float* f1 = (const float*)&v1;
#pragma unroll
  for (int e = 0; e < 4; ++e) {
    float x = f0[e];
    _Float16 hi = (_Float16)x;
    h[e] = hi; l[e] = (_Float16)((x - (float)hi) * LO_SCALE);
    x = f1[e];
    hi = (_Float16)x;
    h[e + 4] = hi; l[e + 4] = (_Float16)((x - (float)hi) * LO_SCALE);
  }
  size_t tb = (size_t)(chunk * NT + ntile) * TILE_H;
  *(half8*)(dst + tb + rem8 * 8) = h;
  *(half8*)(dst + tb + 8192 + rem8 * 8) = l;
}

// ---------------- per-step argmin: direct-L2 B-reads, no tile staging ----------
// 4 waves: pair p = wave>>1 owns rows [32p,32p+32); kh = wave&1 owns a K-half.
// 64 mtiles x 8 chunks = 512 blocks = 2/CU; chunk = blockIdx&7 pins the 4MB
// chunk image to one XCD's L2 (written there by k_cvt, read in tile-lockstep).
__global__ __launch_bounds__(256, 2) void k_argmin_pc(
    const _Float16* __restrict__ rhi, const _Float16* __restrict__ rlo,
    const _Float16* __restrict__ cvt,
    const float* __restrict__ cnorm,
    float* __restrict__ partmin, int* __restrict__ partidx) {
  __shared__ float Xs[2][2048];   // [nt-parity][((pair*2+kh)*2+mt)*64+lane] f32x4 : 16KB
  __shared__ float CN[CHUNK];     // 8KB code norms

  const int tid   = threadIdx.x;
  const int lane  = tid & 63;
  const int wave  = tid >> 6;          // 0..3
  const int pairp = wave >> 1;         // 0..1
  const int kh    = wave & 1;
  const int mtile = blockIdx.x >> 3;   // 0..63
  const int chunk = blockIdx.x & 7;    // XCD-pinned chunk
  const int cbase = chunk * CHUNK;
  const char* ctile = (const char*)(cvt + (size_t)chunk * NT * TILE_H);

  // stage cnorm chunk to LDS
  {
    const float4* s = (const float4*)(cnorm + cbase);
    float4* d = (float4*)CN;
    d[tid] = s[tid];
    d[tid + 256] = s[tid + 256];
  }

  // A fragments: 32 rows (2 mtiles), own K-half. lane: row=lane&15, kb=(lane>>4)*8
  const int kb = (lane >> 4) * 8;
  half8 ah[2][8], al[2][8];
#pragma unroll
  for (int mt = 0; mt < 2; ++mt) {
    const size_t rbase =
        (size_t)(mtile * BM + pairp * 32 + mt * 16 + (lane & 15)) * DIM + kh * 256;
#pragma unroll
    for (int t = 0; t < 8; ++t) {
      ah[mt][t] = *(const half8*)(rhi + rbase + t * 32 + kb);
      al[mt][t] = *(const half8*)(rlo + rbase + t * 32 + kb);
    }
  }
  __syncthreads();   // CN visible

  // per-lane base within a tile for this wave's K-half
  const int lhalf = kh * 8192 + lane * 16;     // hi-image byte offset; lo at +16384

  const int rcode = lane & 15;
  float rmin[2][4] = {{3.4e38f, 3.4e38f, 3.4e38f, 3.4e38f},
                      {3.4e38f, 3.4e38f, 3.4e38f, 3.4e38f}};
  int   ridx[2][4] = {{0, 0, 0, 0}, {0, 0, 0, 0}};

  // two register stages, each one half-tile (t-quartet) of this wave's K-half
  half8 s0h[4], s0l[4], s1h[4], s1l[4];

#define LOAD_HT(SH, SL, NTI, H)                                              \
  {                                                                          \
    const char* bp_ = ctile + (size_t)(NTI) * TILE_B + lhalf + (H) * 4096;   \
    _Pragma("unroll")                                                        \
    for (int j_ = 0; j_ < 4; ++j_) {                                         \
      SH[j_] = *(const half8*)(bp_ + j_ * 1024);                             \
      SL[j_] = *(const half8*)(bp_ + 16384 + j_ * 1024);                     \
    }                                                                        \
  }

#define MFMA_HT(SH, SL, TB)                                                  \
  {                                                                          \
    _Pragma("unroll")                                                        \
    for (int j_ = 0; j_ < 4; ++j_) {                                         \
      _Pragma("unroll")                                                      \
      for (int mt_ = 0; mt_ < 2; ++mt_) {                                    \
        acch[mt_]  = MFMA_F16(ah[mt_][(TB) + j_], SH[j_], acch[mt_], 0, 0, 0);  \
        accl0[mt_] = MFMA_F16(ah[mt_][(TB) + j_], SL[j_], accl0[mt_], 0, 0, 0); \
        accl1[mt_] = MFMA_F16(al[mt_][(TB) + j_], SH[j_], accl1[mt_], 0, 0, 0); \
      }                                                                      \
    }                                                                        \
  }

  // prologue: first half-tile of tile 0
  LOAD_HT(s0h, s0l, 0, 0);

  for (int nt = 0; nt < NT; ++nt) {
    f32x4 acch[2], accl0[2], accl1[2];
#pragma unroll
    for (int mt = 0; mt < 2; ++mt) {
      acch[mt]  = (f32x4){0.f, 0.f, 0.f, 0.f};
      accl0[mt] = (f32x4){0.f, 0.f, 0.f, 0.f};
      accl1[mt] = (f32x4){0.f, 0.f, 0.f, 0.f};
    }

    LOAD_HT(s1h, s1l, nt, 1);          // prefetch 2nd half of current tile
    MFMA_HT(s0h, s0l, 0);              // compute 1st half (loaded last iter)
    const int pn = (nt + 1 < NT) ? nt + 1 : nt;
    LOAD_HT(s0h, s0l, pn, 0);          // prefetch 1st half of next tile
    MFMA_HT(s1h, s1l, 4);              // compute 2nd half

    // pre-combined half-distance dot terms; exchange within the pair
    const int par = nt & 1;
    f32x4 dh[2];
#pragma unroll
    for (int mt = 0; mt < 2; ++mt) {
      dh[mt] = acch[mt] + (accl0[mt] + accl1[mt]) * LO_INV;
      *(f32x4*)&Xs[par][(((pairp * 2 + kh) * 2 + mt) * 64 + lane) * 4] = dh[mt];
    }
    asm volatile("s_waitcnt lgkmcnt(0)" ::: "memory");  // Xs visible; vmem untouched
    __builtin_amdgcn_s_barrier();
    __builtin_amdgcn_sched_barrier(0);

    const float cn = CN[nt * 16 + rcode];
    const int codeg = cbase + nt * 16 + rcode;
#pragma unroll
    for (int mt = 0; mt < 2; ++mt) {
      f32x4 dp = *(const f32x4*)&Xs[par][(((pairp * 2 + (kh ^ 1)) * 2 + mt) * 64 + lane) * 4];
      f32x4 dt = dh[mt] + dp;        // commutative: both waves get identical values
#pragma unroll
      for (int r = 0; r < 4; ++r) {
        float d = cn - 2.0f * dt[r];
        if (d < rmin[mt][r]) { rmin[mt][r] = d; ridx[mt][r] = codeg; }  // first-min
      }
    }
  }
#undef LOAD_HT
#undef MFMA_HT

  // butterfly min across the 16-lane column group (tie -> smaller index)
#pragma unroll
  for (int s = 1; s < 16; s <<= 1) {
#pragma unroll
    for (int mt = 0; mt < 2; ++mt) {
#pragma unroll
      for (int r = 0; r < 4; ++r) {
        float ov = __shfl_xor(rmin[mt][r], s);
        int   oi = __shfl_xor(ridx[mt][r], s);
        if (ov < rmin[mt][r] || (ov == rmin[mt][r] && oi < ridx[mt][r])) {
          rmin[mt][r] = ov; ridx[mt][r] = oi;
        }
      }
    }
  }
  if (kh == 0 && (lane & 15) == 0) {
#pragma unroll
    for (int mt = 0; mt < 2; ++mt) {
      int rowbase = mtile * BM + pairp * 32 + mt * 16 + (lane >> 4) * 4;
#pragma unroll
      for (int r = 0; r < 4; ++r) {
        partmin[(size_t)(rowbase + r) * NCHUNK + chunk] = rmin[mt][r];
        partidx[(size_t)(rowbase + r) * NCHUNK + chunk] = ridx[mt][r];
      }
    }
  }
}

// ---------------- fallback argmin (round-1 structure, inline conversion) ----------------
__device__ __forceinline__ void load8(const float* __restrict__ cb, int cbase, int nt,
                                      int s_code, int s_kseg, float4 v[8]) {
  const float4* src = (const float4*)(cb + (size_t)(cbase + nt * 16 + s_code) * DIM + s_kseg);
#pragma unroll
  for (int j = 0; j < 8; ++j) v[j] = src[j];
}

__device__ __forceinline__ void cvt_store(_Float16* __restrict__ BHbuf,
                                          _Float16* __restrict__ BLbuf,
                                          int code, int kseg, const float4 sv[8]) {
  const float* f = (const float*)sv;
#pragma unroll
  for (int j = 0; j < 4; ++j) {
    half8 h, l;
#pragma unroll
    for (int e = 0; e < 8; ++e) {
      float x = f[j * 8 + e];
      _Float16 hi = (_Float16)x;
      h[e] = hi;
      l[e] = (_Float16)((x - (float)hi) * LO_SCALE);
    }
    int hw = swz(code, kseg + j * 8);
    *(half8*)(BHbuf + hw) = h;
    *(half8*)(BLbuf + hw) = l;
  }
}

__global__ __launch_bounds__(256, 2) void k_argmin_fb(
    const _Float16* __restrict__ rhi, const _Float16* __restrict__ rlo,
    const float* __restrict__ cb, const float* __restrict__ cnorm,
    float* __restrict__ partmin, int* __restrict__ partidx) {
  __shared__ _Float16 BH[2][16 * DIM];
  __shared__ _Float16 BL[2][16 * DIM];
  __shared__ float CN[CHUNK];

  const int tid   = threadIdx.x;
  const int lane  = tid & 63;
  const int wave  = tid >> 6;
  const int mtile = blockIdx.x >> 3;
  const int chunk = blockIdx.x & 7;
  const int cbase = chunk * CHUNK;

  {
    const float4* s = (const float4*)(cnorm + cbase);
    float4* d = (float4*)CN;
    for (int i = tid; i < CHUNK / 4; i += 256) d[i] = s[i];
  }

  const int arow = mtile * 64 + wave * 16 + (lane & 15);
  const int kb = (lane >> 4) * 8;
  half8 ah[16], al[16];
#pragma unroll
  for (int t = 0; t < 16; ++t) {
    ah[t] = *(const half8*)(rhi + (size_t)arow * DIM + t * 32 + kb);
    al[t] = *(const half8*)(rlo + (size_t)arow * DIM + t * 32 + kb);
  }

  const int s_code = tid >> 4;
  const int s_kseg = (tid & 15) * 32;

  float rmin[4] = {3.4e38f, 3.4e38f, 3.4e38f, 3.4e38f};
  int   ridx[4] = {0, 0, 0, 0};

  {
    float4 v0[8];
    load8(cb, cbase, 0, s_code, s_kseg, v0);
    cvt_store(&BH[0][0], &BL[0][0], s_code, s_kseg, v0);
  }

  const int rcode = lane & 15;
  for (int nt = 0; nt < NT; ++nt) {
    __syncthreads();
    const int cur = nt & 1;
    const bool more = (nt + 1 < NT);
    float4 nv[8];
    if (more) load8(cb, cbase, nt + 1, s_code, s_kseg, nv);

    f32x4 acch  = {0.f, 0.f, 0.f, 0.f};
    f32x4 accl0 = {0.f, 0.f, 0.f, 0.f};
    f32x4 accl1 = {0.f, 0.f, 0.f, 0.f};
    const _Float16* bh = &BH[cur][0];
    const _Float16* bl = &BL[cur][0];
#pragma unroll
    for (int t = 0; t < 16; ++t) {
      const int hw = swz(rcode, t * 32 + kb);
      half8 fbh = *(const half8*)(bh + hw);
      half8 fbl = *(const half8*)(bl + hw);
      acch  = MFMA_F16(ah[t], fbh, acch, 0, 0, 0);
      accl0 = MFMA_F16(ah[t], fbl, accl0, 0, 0, 0);
      accl1 = MFMA_F16(al[t], fbh, accl1, 0, 0, 0);
    }
    float cn = CN[nt * 16 + rcode];
    int codeg = cbase + nt * 16 + rcode;
#pragma unroll
    for (int r = 0; r < 4; ++r) {
      float d = cn - 2.0f * (acch[r] + (accl0[r] + accl1[r]) * LO_INV);
      if (d < rmin[r]) { rmin[r] = d; ridx[r] = codeg; }
    }
    if (more) cvt_store(&BH[cur ^ 1][0], &BL[cur ^ 1][0], s_code, s_kseg, nv);
  }

#pragma unroll
  for (int s = 1; s < 16; s <<= 1) {
#pragma unroll
    for (int r = 0; r < 4; ++r) {
      float ov = __shfl_xor(rmin[r], s);
      int   oi = __shfl_xor(ridx[r], s);
      if (ov < rmin[r] || (ov == rmin[r] && oi < ridx[r])) { rmin[r] = ov; ridx[r] = oi; }
    }
  }
  if ((lane & 15) == 0) {
    int rowbase = mtile * 64 + wave * 16 + (lane >> 4) * 4;
#pragma unroll
    for (int r = 0; r < 4; ++r) {
      partmin[(size_t)(rowbase + r) * NCHUNK + chunk] = rmin[r];
      partidx[(size_t)(rowbase + r) * NCHUNK + chunk] = ridx[r];
    }
  }
}

// ---------------- reduce chunks, gather, update residual/quantized/loss ----------------
__global__ __launch_bounds__(256) void k_update(
    const float* __restrict__ cb, const float* __restrict__ z,
    const float* __restrict__ partmin, const int* __restrict__ partidx,
    float* __restrict__ resid, _Float16* __restrict__ rhi, _Float16* __restrict__ rlo,
    float* __restrict__ quant, float* __restrict__ out_idx,
    float* __restrict__ losspart, int step) {
  __shared__ int s_idx[16];
  __shared__ float s_red[4];
  const int tid = threadIdx.x;
  const int row0 = blockIdx.x * 16;

  if (tid < 16) {
    const int row = row0 + tid;
    float bv = partmin[(size_t)row * NCHUNK];
    int   bi = partidx[(size_t)row * NCHUNK];
#pragma unroll
    for (int c = 1; c < NCHUNK; ++c) {
      float v = partmin[(size_t)row * NCHUNK + c];
      int   i = partidx[(size_t)row * NCHUNK + c];
      if (v < bv || (v == bv && i < bi)) { bv = v; bi = i; }
    }
    s_idx[tid] = bi;
    out_idx[(size_t)row * NCB + step] = (float)bi;
  }
  __syncthreads();

  float lsum = 0.f;
  const int sub = tid >> 7;     // 0/1: which row of the pair
  const int e   = tid & 127;    // float4 index within row
  for (int rp = 0; rp < 16; rp += 2) {
    const int rl = rp + sub;
    const int row = row0 + rl;
    const int idx = s_idx[rl];
    float4 q  = ((const float4*)cb)[(size_t)idx * 128 + e];
    float4 zv = ((const float4*)z)[(size_t)row * 128 + e];
    float4 rv = ((const float4*)resid)[(size_t)row * 128 + e];
    float4 nr, qa;
    const float* qf = (const float*)&q;
    const float* zf = (const float*)&zv;
    const float* rf = (const float*)&rv;
    float* nf = (float*)&nr;
    float* af = (float*)&qa;
    if (step == 0) {
#pragma unroll
      for (int j = 0; j < 4; ++j) af[j] = qf[j];
    } else {
      float4 old = ((const float4*)quant)[(size_t)row * 128 + e];
      const float* of = (const float*)&old;
#pragma unroll
      for (int j = 0; j < 4; ++j) af[j] = of[j] + qf[j];
    }
    ((float4*)quant)[(size_t)row * 128 + e] = qa;
    half4v h, l;
#pragma unroll
    for (int j = 0; j < 4; ++j) {
      float nrj = rf[j] - qf[j];
      nf[j] = nrj;
      _Float16 hi = (_Float16)nrj;
      h[j] = hi;
      l[j] = (_Float16)((nrj - (float)hi) * LO_SCALE);
      float dq = qf[j] - zf[j];
      lsum += dq * dq;
    }
    ((float4*)resid)[(size_t)row * 128 + e] = nr;
    *(half4v*)&rhi[(size_t)row * DIM + e * 4] = h;
    *(half4v*)&rlo[(size_t)row * DIM + e * 4] = l;
  }
#pragma unroll
  for (int off = 32; off; off >>= 1) lsum += __shfl_down(lsum, off);
  if ((tid & 63) == 0) s_red[tid >> 6] = lsum;
  __syncthreads();
  if (tid == 0) losspart[blockIdx.x] = s_red[0] + s_red[1] + s_red[2] + s_red[3];
}

// ---------------- final loss ----------------
__global__ void k_loss(const float* __restrict__ losspart, float* __restrict__ out_loss) {
  if (threadIdx.x == 0 && blockIdx.x == 0) {
    double t = 0.0;
    for (int i = 0; i < NCB * 256; ++i) t += (double)losspart[i];
    out_loss[0] = (float)(t * (1.25 / (double)((size_t)BATCH * DIM)));
  }
}

extern "C" void kernel_launch(void* const* d_in, const int* in_sizes, int n_in,
                              void* d_out, int out_size, void* d_ws, size_t ws_size,
                              hipStream_t stream) {
  const float* z  = (const float*)d_in[0];
  const float* cb = (const float*)d_in[1];
  float* out = (float*)d_out;
  float* quant    = out;                           // [4096*512]
  float* out_loss = out + (size_t)BATCH * DIM;     // [1]
  float* out_idx  = out + (size_t)BATCH * DIM + 1; // [4096*8] written as float

  char* ws = (char*)d_ws;
  float*    resid    = (float*)ws;                                  // 8 MB
  _Float16* rhi      = (_Float16*)(ws + ((size_t)8  << 20));        // 4 MB
  _Float16* rlo      = (_Float16*)(ws + ((size_t)12 << 20));        // 4 MB
  float*    cnorm    = (float*)(ws + ((size_t)16 << 20));           // 512 KB
  float*    partmin  = (float*)(ws + ((size_t)16 << 20) + (512 << 10)); // 128 KB
  int*      partidx  = (int*)  (ws + ((size_t)16 << 20) + (640 << 10)); // 128 KB
  float*    losspart = (float*)(ws + ((size_t)16 << 20) + (768 << 10)); // 8 KB
  _Float16* cvtbuf   = (_Float16*)(ws + ((size_t)20 << 20));        // 32 MB

  const size_t REQ = ((size_t)20 << 20) + ((size_t)32 << 20);
  const bool pre = (ws_size >= REQ);

  k_init<<<dim3((BATCH * DIM / 4) / 256), dim3(256), 0, stream>>>(z, resid, rhi, rlo);
  k_cnorm<<<dim3(NCB * CODES / 4), dim3(256), 0, stream>>>(cb, cnorm);

  for (int k = 0; k < NCB; ++k) {
    const float* cbk = cb + (size_t)k * CODES * DIM;
    if (pre) {
      k_cvt<<<dim3(CODES * 64 / 256), dim3(256), 0, stream>>>(cbk, cvtbuf);
      k_argmin_pc<<<dim3((BATCH / BM) * NCHUNK), dim3(256), 0, stream>>>(
          rhi, rlo, cvtbuf, cnorm + (size_t)k * CODES, partmin, partidx);
    } else {
      k_argmin_fb<<<dim3((BATCH / 64) * NCHUNK), dim3(256), 0, stream>>>(
          rhi, rlo, cbk, cnorm + (size_t)k * CODES, partmin, partidx);
    }
    k_update<<<dim3(BATCH / 16), dim3(256), 0, stream>>>(
        cbk, z, partmin, partidx, resid, rhi, rlo,
        quant, out_idx, losspart + k * 256, k);
  }
  k_loss<<<dim3(1), dim3(64), 0, stream>>>(losspart, out_loss);
}

// Round 7
// 1743.191 us; speedup vs baseline: 1.1921x; 1.0896x over previous
//
#include <hip/hip_runtime.h>

typedef _Float16 half8 __attribute__((ext_vector_type(8)));
typedef _Float16 half4v __attribute__((ext_vector_type(4)));
typedef float f32x4 __attribute__((ext_vector_type(4)));

#define MFMA_F16 __builtin_amdgcn_mfma_f32_16x16x32_f16

static constexpr int BATCH  = 4096;
static constexpr int DIM    = 512;
static constexpr int CODES  = 16384;
static constexpr int NCB    = 8;
static constexpr int NCHUNK = 8;
static constexpr int CHUNK  = CODES / NCHUNK;   // 2048
static constexpr int NT     = CHUNK / 16;       // 128 tiles of 16 codes
static constexpr int BM     = 64;               // rows per block (one 4-wave K-split group)
static constexpr int TILE_H = 16384;            // halfs per tile (hi 8192 | lo 8192) = 32KB
static constexpr int TILE_B = 32768;            // tile bytes
static constexpr float LO_SCALE = 2048.0f;
static constexpr float LO_INV   = 1.0f / 2048.0f;

// legacy swizzle (fallback path only)
__device__ __forceinline__ int swz(int code, int kk) {
  return code * DIM + (kk ^ (((code ^ (kk >> 6)) & 7) << 3));
}

// ---------------- init: residual = z, plus f16 hi/lo split ----------------
__global__ __launch_bounds__(256) void k_init(const float* __restrict__ z,
                                              float* __restrict__ resid,
                                              _Float16* __restrict__ rhi,
                                              _Float16* __restrict__ rlo) {
  int i = blockIdx.x * 256 + threadIdx.x;      // float4 index, 524288 total
  float4 v = ((const float4*)z)[i];
  ((float4*)resid)[i] = v;
  half4v h, l;
  const float* vf = (const float*)&v;
#pragma unroll
  for (int j = 0; j < 4; ++j) {
    float x = vf[j];
    _Float16 hi = (_Float16)x;
    h[j] = hi;
    l[j] = (_Float16)((x - (float)hi) * LO_SCALE);
  }
  *(half4v*)&rhi[(size_t)i * 4] = h;
  *(half4v*)&rlo[(size_t)i * 4] = l;
}

// ---------------- codebook squared norms (f64 accumulate) ----------------
__global__ __launch_bounds__(256) void k_cnorm(const float* __restrict__ cb,
                                               float* __restrict__ cnorm) {
  int wave = threadIdx.x >> 6, lane = threadIdx.x & 63;
  int code = blockIdx.x * 4 + wave;            // 131072 codes total
  const float4* src = (const float4*)(cb + (size_t)code * DIM);
  double s = 0.0;
#pragma unroll
  for (int j = 0; j < 2; ++j) {
    float4 v = src[lane * 2 + j];
    s += (double)v.x * v.x + (double)v.y * v.y + (double)v.z * v.z + (double)v.w * v.w;
  }
#pragma unroll
  for (int off = 32; off; off >>= 1) s += __shfl_down(s, off);
  if (lane == 0) cnorm[code] = (float)s;
}

// ---------------- preconvert codebook k: lane-linear tile images ----------------
// Per 16-code tile: hi image halfs [0,8192): pos = t*512 + kbg*128 + code*8 + e
// (t: K-slice of 32, kbg = k-quarter-within-slice, e in [0,8)); lo image at +8192.
// Hot-loop read for lane l, slice t is byte (t*1024 + l*16) — fully linear.
__global__ __launch_bounds__(256) void k_cvt(const float* __restrict__ cb,
                                             _Float16* __restrict__ dst) {
  const int chunk = blockIdx.x & 7;                        // XCD-pinned
  const int idx8  = (blockIdx.x >> 3) * 256 + threadIdx.x; // [0, 131072) half8-slots
  const int ntile = idx8 >> 10;
  const int rem8  = idx8 & 1023;
  const int p     = rem8 * 8;
  const int t     = p >> 9;
  const int kbg   = (p >> 7) & 3;
  const int code  = (p >> 3) & 15;
  const int code_g = chunk * CHUNK + ntile * 16 + code;
  const float* src = cb + (size_t)code_g * DIM + t * 32 + kbg * 8;
  float4 v0 = *(const float4*)src;
  float4 v1 = *(const float4*)(src + 4);
  half8 h, l;
  const float* f0 = (const float*)&v0;
  const float* f1 = (const float*)&v1;
#pragma unroll
  for (int e = 0; e < 4; ++e) {
    float x = f0[e];
    _Float16 hi = (_Float16)x;
    h[e] = hi; l[e] = (_Float16)((x - (float)hi) * LO_SCALE);
    x = f1[e];
    hi = (_Float16)x;
    h[e + 4] = hi; l[e + 4] = (_Float16)((x - (float)hi) * LO_SCALE);
  }
  size_t tb = (size_t)(chunk * NT + ntile) * TILE_H;
  *(half8*)(dst + tb + rem8 * 8) = h;
  *(half8*)(dst + tb + 8192 + rem8 * 8) = l;
}

// ---------------- per-step argmin: direct-L2 B-reads, 4-way K-split group ----------
// 4 waves: wave kq owns ALL 64 block rows x K-quarter [kq*128,(kq+1)*128).
// Wave kq keeps the argmin for its own 16-row band (mt == kq); partial dots
// for the other bands are exchanged through parity-double-buffered Xs.
// 64 mtiles x 8 chunks = 512 blocks = 2/CU; chunk = blockIdx&7 pins the 4MB
// chunk image to one XCD's L2 (written there by k_cvt, read in tile-lockstep).
__global__ __launch_bounds__(256, 2) void k_argmin_pc(
    const _Float16* __restrict__ rhi, const _Float16* __restrict__ rlo,
    const _Float16* __restrict__ cvt,
    const float* __restrict__ cnorm,
    float* __restrict__ partmin, int* __restrict__ partidx) {
  __shared__ float Xs[2][4096];   // [par][((kq*4+mt)*64+lane)*4] : 32KB
  __shared__ float CN[CHUNK];     // 8KB code norms

  const int tid   = threadIdx.x;
  const int lane  = tid & 63;
  const int kq    = tid >> 6;          // 0..3 : this wave's K-quarter
  const int mtile = blockIdx.x >> 3;   // 0..63
  const int chunk = blockIdx.x & 7;    // XCD-pinned chunk
  const int cbase = chunk * CHUNK;
  const char* ctile = (const char*)(cvt + (size_t)chunk * NT * TILE_H);

  // stage cnorm chunk to LDS
  {
    const float4* s = (const float4*)(cnorm + cbase);
    float4* d = (float4*)CN;
    d[tid] = s[tid];
    d[tid + 256] = s[tid + 256];
  }

  // A fragments: 64 rows (4 bands of 16) x own K-quarter.
  // lane: row=lane&15, kb=(lane>>4)*8 within each 32-k slice.
  const int kb = (lane >> 4) * 8;
  half8 ah[4][4], al[4][4];
#pragma unroll
  for (int mt = 0; mt < 4; ++mt) {
    const size_t rbase =
        (size_t)(mtile * BM + mt * 16 + (lane & 15)) * DIM + kq * 128;
#pragma unroll
    for (int t = 0; t < 4; ++t) {
      ah[mt][t] = *(const half8*)(rhi + rbase + t * 32 + kb);
      al[mt][t] = *(const half8*)(rlo + rbase + t * 32 + kb);
    }
  }
  __syncthreads();   // CN visible (also drains A-loads)

  // per-lane byte base within a tile for this wave's K-quarter (hi image; lo at +16384)
  const int qbase = kq * 4096 + lane * 16;

  const int rcode = lane & 15;
  float rmin[4] = {3.4e38f, 3.4e38f, 3.4e38f, 3.4e38f};
  int   ridx[4] = {0, 0, 0, 0};

  // two register stages, each one half of this wave's K-quarter (2 t-slices)
  half8 s0h[2], s0l[2], s1h[2], s1l[2];

#define LOAD_HT(SH, SL, NTI, H)                                              \
  {                                                                          \
    const char* bp_ = ctile + (size_t)(NTI) * TILE_B + qbase + (H) * 2048;   \
    _Pragma("unroll")                                                        \
    for (int j_ = 0; j_ < 2; ++j_) {                                         \
      SH[j_] = *(const half8*)(bp_ + j_ * 1024);                             \
      SL[j_] = *(const half8*)(bp_ + 16384 + j_ * 1024);                     \
    }                                                                        \
  }

#define MFMA_HT(SH, SL, TB)                                                  \
  {                                                                          \
    _Pragma("unroll")                                                        \
    for (int j_ = 0; j_ < 2; ++j_) {                                         \
      _Pragma("unroll")                                                      \
      for (int mt_ = 0; mt_ < 4; ++mt_) {                                    \
        acch[mt_]  = MFMA_F16(ah[mt_][(TB) + j_], SH[j_], acch[mt_], 0, 0, 0);  \
        accl0[mt_] = MFMA_F16(ah[mt_][(TB) + j_], SL[j_], accl0[mt_], 0, 0, 0); \
        accl1[mt_] = MFMA_F16(al[mt_][(TB) + j_], SH[j_], accl1[mt_], 0, 0, 0); \
      }                                                                      \
    }                                                                        \
  }

  // prologue: first half of tile 0's quarter
  LOAD_HT(s0h, s0l, 0, 0);

  for (int nt = 0; nt < NT; ++nt) {
    f32x4 acch[4], accl0[4], accl1[4];
#pragma unroll
    for (int mt = 0; mt < 4; ++mt) {
      acch[mt]  = (f32x4){0.f, 0.f, 0.f, 0.f};
      accl0[mt] = (f32x4){0.f, 0.f, 0.f, 0.f};
      accl1[mt] = (f32x4){0.f, 0.f, 0.f, 0.f};
    }

    LOAD_HT(s1h, s1l, nt, 1);          // prefetch 2nd half of current quarter
    MFMA_HT(s0h, s0l, 0);              // compute 1st half (loaded last iter)
    const int pn = (nt + 1 < NT) ? nt + 1 : nt;
    LOAD_HT(s0h, s0l, pn, 0);          // prefetch 1st half of next tile
    MFMA_HT(s1h, s1l, 2);              // compute 2nd half

    // quarter-dot partials for all 4 bands -> Xs; exchange across the 4 waves
    const int par = nt & 1;
#pragma unroll
    for (int mt = 0; mt < 4; ++mt) {
      f32x4 dh = acch[mt] + (accl0[mt] + accl1[mt]) * LO_INV;
      *(f32x4*)&Xs[par][((kq * 4 + mt) * 64 + lane) * 4] = dh;
    }
    asm volatile("s_waitcnt lgkmcnt(0)" ::: "memory");  // Xs visible; vmem untouched
    __builtin_amdgcn_s_barrier();
    __builtin_amdgcn_sched_barrier(0);

    // own band (mt == kq): fixed-order sum of the 4 quarter partials
    f32x4 dt = {0.f, 0.f, 0.f, 0.f};
#pragma unroll
    for (int kq2 = 0; kq2 < 4; ++kq2)
      dt += *(const f32x4*)&Xs[par][((kq2 * 4 + kq) * 64 + lane) * 4];

    const float cn = CN[nt * 16 + rcode];
    const int codeg = cbase + nt * 16 + rcode;
#pragma unroll
    for (int r = 0; r < 4; ++r) {
      float d = cn - 2.0f * dt[r];
      if (d < rmin[r]) { rmin[r] = d; ridx[r] = codeg; }   // ascending -> first-min
    }
  }
#undef LOAD_HT
#undef MFMA_HT

  // butterfly min across the 16-lane column group (tie -> smaller index)
#pragma unroll
  for (int s = 1; s < 16; s <<= 1) {
#pragma unroll
    for (int r = 0; r < 4; ++r) {
      float ov = __shfl_xor(rmin[r], s);
      int   oi = __shfl_xor(ridx[r], s);
      if (ov < rmin[r] || (ov == rmin[r] && oi < ridx[r])) { rmin[r] = ov; ridx[r] = oi; }
    }
  }
  if ((lane & 15) == 0) {
    const int rowbase = mtile * BM + kq * 16 + (lane >> 4) * 4;
#pragma unroll
    for (int r = 0; r < 4; ++r) {
      partmin[(size_t)(rowbase + r) * NCHUNK + chunk] = rmin[r];
      partidx[(size_t)(rowbase + r) * NCHUNK + chunk] = ridx[r];
    }
  }
}

// ---------------- fallback argmin (round-1 structure, inline conversion) ----------------
__device__ __forceinline__ void load8(const float* __restrict__ cb, int cbase, int nt,
                                      int s_code, int s_kseg, float4 v[8]) {
  const float4* src = (const float4*)(cb + (size_t)(cbase + nt * 16 + s_code) * DIM + s_kseg);
#pragma unroll
  for (int j = 0; j < 8; ++j) v[j] = src[j];
}

__device__ __forceinline__ void cvt_store(_Float16* __restrict__ BHbuf,
                                          _Float16* __restrict__ BLbuf,
                                          int code, int kseg, const float4 sv[8]) {
  const float* f = (const float*)sv;
#pragma unroll
  for (int j = 0; j < 4; ++j) {
    half8 h, l;
#pragma unroll
    for (int e = 0; e < 8; ++e) {
      float x = f[j * 8 + e];
      _Float16 hi = (_Float16)x;
      h[e] = hi;
      l[e] = (_Float16)((x - (float)hi) * LO_SCALE);
    }
    int hw = swz(code, kseg + j * 8);
    *(half8*)(BHbuf + hw) = h;
    *(half8*)(BLbuf + hw) = l;
  }
}

__global__ __launch_bounds__(256, 2) void k_argmin_fb(
    const _Float16* __restrict__ rhi, const _Float16* __restrict__ rlo,
    const float* __restrict__ cb, const float* __restrict__ cnorm,
    float* __restrict__ partmin, int* __restrict__ partidx) {
  __shared__ _Float16 BH[2][16 * DIM];
  __shared__ _Float16 BL[2][16 * DIM];
  __shared__ float CN[CHUNK];

  const int tid   = threadIdx.x;
  const int lane  = tid & 63;
  const int wave  = tid >> 6;
  const int mtile = blockIdx.x >> 3;
  const int chunk = blockIdx.x & 7;
  const int cbase = chunk * CHUNK;

  {
    const float4* s = (const float4*)(cnorm + cbase);
    float4* d = (float4*)CN;
    for (int i = tid; i < CHUNK / 4; i += 256) d[i] = s[i];
  }

  const int arow = mtile * 64 + wave * 16 + (lane & 15);
  const int kb = (lane >> 4) * 8;
  half8 ah[16], al[16];
#pragma unroll
  for (int t = 0; t < 16; ++t) {
    ah[t] = *(const half8*)(rhi + (size_t)arow * DIM + t * 32 + kb);
    al[t] = *(const half8*)(rlo + (size_t)arow * DIM + t * 32 + kb);
  }

  const int s_code = tid >> 4;
  const int s_kseg = (tid & 15) * 32;

  float rmin[4] = {3.4e38f, 3.4e38f, 3.4e38f, 3.4e38f};
  int   ridx[4] = {0, 0, 0, 0};

  {
    float4 v0[8];
    load8(cb, cbase, 0, s_code, s_kseg, v0);
    cvt_store(&BH[0][0], &BL[0][0], s_code, s_kseg, v0);
  }

  const int rcode = lane & 15;
  for (int nt = 0; nt < NT; ++nt) {
    __syncthreads();
    const int cur = nt & 1;
    const bool more = (nt + 1 < NT);
    float4 nv[8];
    if (more) load8(cb, cbase, nt + 1, s_code, s_kseg, nv);

    f32x4 acch  = {0.f, 0.f, 0.f, 0.f};
    f32x4 accl0 = {0.f, 0.f, 0.f, 0.f};
    f32x4 accl1 = {0.f, 0.f, 0.f, 0.f};
    const _Float16* bh = &BH[cur][0];
    const _Float16* bl = &BL[cur][0];
#pragma unroll
    for (int t = 0; t < 16; ++t) {
      const int hw = swz(rcode, t * 32 + kb);
      half8 fbh = *(const half8*)(bh + hw);
      half8 fbl = *(const half8*)(bl + hw);
      acch  = MFMA_F16(ah[t], fbh, acch, 0, 0, 0);
      accl0 = MFMA_F16(ah[t], fbl, accl0, 0, 0, 0);
      accl1 = MFMA_F16(al[t], fbh, accl1, 0, 0, 0);
    }
    float cn = CN[nt * 16 + rcode];
    int codeg = cbase + nt * 16 + rcode;
#pragma unroll
    for (int r = 0; r < 4; ++r) {
      float d = cn - 2.0f * (acch[r] + (accl0[r] + accl1[r]) * LO_INV);
      if (d < rmin[r]) { rmin[r] = d; ridx[r] = codeg; }
    }
    if (more) cvt_store(&BH[cur ^ 1][0], &BL[cur ^ 1][0], s_code, s_kseg, nv);
  }

#pragma unroll
  for (int s = 1; s < 16; s <<= 1) {
#pragma unroll
    for (int r = 0; r < 4; ++r) {
      float ov = __shfl_xor(rmin[r], s);
      int   oi = __shfl_xor(ridx[r], s);
      if (ov < rmin[r] || (ov == rmin[r] && oi < ridx[r])) { rmin[r] = ov; ridx[r] = oi; }
    }
  }
  if ((lane & 15) == 0) {
    int rowbase = mtile * 64 + wave * 16 + (lane >> 4) * 4;
#pragma unroll
    for (int r = 0; r < 4; ++r) {
      partmin[(size_t)(rowbase + r) * NCHUNK + chunk] = rmin[r];
      partidx[(size_t)(rowbase + r) * NCHUNK + chunk] = ridx[r];
    }
  }
}

// ---------------- reduce chunks, gather, update residual/quantized/loss ----------------
__global__ __launch_bounds__(256) void k_update(
    const float* __restrict__ cb, const float* __restrict__ z,
    const float* __restrict__ partmin, const int* __restrict__ partidx,
    float* __restrict__ resid, _Float16* __restrict__ rhi, _Float16* __restrict__ rlo,
    float* __restrict__ quant, float* __restrict__ out_idx,
    float* __restrict__ losspart, int step) {
  __shared__ int s_idx[16];
  __shared__ float s_red[4];
  const int tid = threadIdx.x;
  const int row0 = blockIdx.x * 16;

  if (tid < 16) {
    const int row = row0 + tid;
    float bv = partmin[(size_t)row * NCHUNK];
    int   bi = partidx[(size_t)row * NCHUNK];
#pragma unroll
    for (int c = 1; c < NCHUNK; ++c) {
      float v = partmin[(size_t)row * NCHUNK + c];
      int   i = partidx[(size_t)row * NCHUNK + c];
      if (v < bv || (v == bv && i < bi)) { bv = v; bi = i; }
    }
    s_idx[tid] = bi;
    out_idx[(size_t)row * NCB + step] = (float)bi;
  }
  __syncthreads();

  float lsum = 0.f;
  const int sub = tid >> 7;     // 0/1: which row of the pair
  const int e   = tid & 127;    // float4 index within row
  for (int rp = 0; rp < 16; rp += 2) {
    const int rl = rp + sub;
    const int row = row0 + rl;
    const int idx = s_idx[rl];
    float4 q  = ((const float4*)cb)[(size_t)idx * 128 + e];
    float4 zv = ((const float4*)z)[(size_t)row * 128 + e];
    float4 rv = ((const float4*)resid)[(size_t)row * 128 + e];
    float4 nr, qa;
    const float* qf = (const float*)&q;
    const float* zf = (const float*)&zv;
    const float* rf = (const float*)&rv;
    float* nf = (float*)&nr;
    float* af = (float*)&qa;
    if (step == 0) {
#pragma unroll
      for (int j = 0; j < 4; ++j) af[j] = qf[j];
    } else {
      float4 old = ((const float4*)quant)[(size_t)row * 128 + e];
      const float* of = (const float*)&old;
#pragma unroll
      for (int j = 0; j < 4; ++j) af[j] = of[j] + qf[j];
    }
    ((float4*)quant)[(size_t)row * 128 + e] = qa;
    half4v h, l;
#pragma unroll
    for (int j = 0; j < 4; ++j) {
      float nrj = rf[j] - qf[j];
      nf[j] = nrj;
      _Float16 hi = (_Float16)nrj;
      h[j] = hi;
      l[j] = (_Float16)((nrj - (float)hi) * LO_SCALE);
      float dq = qf[j] - zf[j];
      lsum += dq * dq;
    }
    ((float4*)resid)[(size_t)row * 128 + e] = nr;
    *(half4v*)&rhi[(size_t)row * DIM + e * 4] = h;
    *(half4v*)&rlo[(size_t)row * DIM + e * 4] = l;
  }
#pragma unroll
  for (int off = 32; off; off >>= 1) lsum += __shfl_down(lsum, off);
  if ((tid & 63) == 0) s_red[tid >> 6] = lsum;
  __syncthreads();
  if (tid == 0) losspart[blockIdx.x] = s_red[0] + s_red[1] + s_red[2] + s_red[3];
}

// ---------------- final loss ----------------
__global__ void k_loss(const float* __restrict__ losspart, float* __restrict__ out_loss) {
  if (threadIdx.x == 0 && blockIdx.x == 0) {
    double t = 0.0;
    for (int i = 0; i < NCB * 256; ++i) t += (double)losspart[i];
    out_loss[0] = (float)(t * (1.25 / (double)((size_t)BATCH * DIM)));
  }
}

extern "C" void kernel_launch(void* const* d_in, const int* in_sizes, int n_in,
                              void* d_out, int out_size, void* d_ws, size_t ws_size,
                              hipStream_t stream) {
  const float* z  = (const float*)d_in[0];
  const float* cb = (const float*)d_in[1];
  float* out = (float*)d_out;
  float* quant    = out;                           // [4096*512]
  float* out_loss = out + (size_t)BATCH * DIM;     // [1]
  float* out_idx  = out + (size_t)BATCH * DIM + 1; // [4096*8] written as float

  char* ws = (char*)d_ws;
  float*    resid    = (float*)ws;                                  // 8 MB
  _Float16* rhi      = (_Float16*)(ws + ((size_t)8  << 20));        // 4 MB
  _Float16* rlo      = (_Float16*)(ws + ((size_t)12 << 20));        // 4 MB
  float*    cnorm    = (float*)(ws + ((size_t)16 << 20));           // 512 KB
  float*    partmin  = (float*)(ws + ((size_t)16 << 20) + (512 << 10)); // 128 KB
  int*      partidx  = (int*)  (ws + ((size_t)16 << 20) + (640 << 10)); // 128 KB
  float*    losspart = (float*)(ws + ((size_t)16 << 20) + (768 << 10)); // 8 KB
  _Float16* cvtbuf   = (_Float16*)(ws + ((size_t)20 << 20));        // 32 MB

  const size_t REQ = ((size_t)20 << 20) + ((size_t)32 << 20);
  const bool pre = (ws_size >= REQ);

  k_init<<<dim3((BATCH * DIM / 4) / 256), dim3(256), 0, stream>>>(z, resid, rhi, rlo);
  k_cnorm<<<dim3(NCB * CODES / 4), dim3(256), 0, stream>>>(cb, cnorm);

  for (int k = 0; k < NCB; ++k) {
    const float* cbk = cb + (size_t)k * CODES * DIM;
    if (pre) {
      k_cvt<<<dim3(CODES * 64 / 256), dim3(256), 0, stream>>>(cbk, cvtbuf);
      k_argmin_pc<<<dim3((BATCH / BM) * NCHUNK), dim3(256), 0, stream>>>(
          rhi, rlo, cvtbuf, cnorm + (size_t)k * CODES, partmin, partidx);
    } else {
      k_argmin_fb<<<dim3((BATCH / 64) * NCHUNK), dim3(256), 0, stream>>>(
          rhi, rlo, cbk, cnorm + (size_t)k * CODES, partmin, partidx);
    }
    k_update<<<dim3(BATCH / 16), dim3(256), 0, stream>>>(
        cbk, z, partmin, partidx, resid, rhi, rlo,
        quant, out_idx, losspart + k * 256, k);
  }
  k_loss<<<dim3(1), dim3(64), 0, stream>>>(losspart, out_loss);
}